// Round 2
// baseline (1562.425 us; speedup 1.0000x reference)
//
#include <hip/hip_runtime.h>
#include <math.h>

#define N_NODES 10000
#define DIN 128
#define HID 32
#define EMB 16

#define TB 512          // threads per block (softmax kernel)
#define RB 3            // rows per block
#define NF4 2500        // N_NODES / 4
#define CHUNKS 5        // ceil(NF4 / TB)

typedef float fx4 __attribute__((ext_vector_type(4)));  // native vector: OK for nontemporal builtins

// ---------------- encoder: H = relu(X@W1+b1)@W2+b2 ; Hn = H/||H|| -----------
__global__ __launch_bounds__(256) void encoder_kernel(
    const float* __restrict__ X, const float* __restrict__ W1,
    const float* __restrict__ b1, const float* __restrict__ W2,
    const float* __restrict__ b2, float* __restrict__ Hout,
    float* __restrict__ Hn)
{
    __shared__ float sW1[DIN * HID];
    __shared__ float sW2[HID * EMB];
    __shared__ float sb1[HID];
    __shared__ float sb2[EMB];
    const int t = threadIdx.x;
    for (int k = t; k < DIN * HID; k += 256) sW1[k] = W1[k];
    for (int k = t; k < HID * EMB; k += 256) sW2[k] = W2[k];
    if (t < HID) sb1[t] = b1[t];
    if (t < EMB) sb2[t] = b2[t];
    __syncthreads();

    const int row = blockIdx.x * 256 + t;
    if (row >= N_NODES) return;

    float h1[HID];
#pragma unroll
    for (int h = 0; h < HID; ++h) h1[h] = sb1[h];

    const float4* xr = (const float4*)(X + (size_t)row * DIN);
#pragma unroll
    for (int k4 = 0; k4 < DIN / 4; ++k4) {
        float4 xv = xr[k4];
        const float* w = &sW1[(k4 * 4) * HID];
#pragma unroll
        for (int h = 0; h < HID; ++h) h1[h] = fmaf(xv.x, w[h], h1[h]);
#pragma unroll
        for (int h = 0; h < HID; ++h) h1[h] = fmaf(xv.y, w[HID + h], h1[h]);
#pragma unroll
        for (int h = 0; h < HID; ++h) h1[h] = fmaf(xv.z, w[2 * HID + h], h1[h]);
#pragma unroll
        for (int h = 0; h < HID; ++h) h1[h] = fmaf(xv.w, w[3 * HID + h], h1[h]);
    }

    float e[EMB];
#pragma unroll
    for (int j = 0; j < EMB; ++j) e[j] = sb2[j];
#pragma unroll
    for (int h = 0; h < HID; ++h) {
        float v = fmaxf(h1[h], 0.0f);
#pragma unroll
        for (int j = 0; j < EMB; ++j) e[j] = fmaf(v, sW2[h * EMB + j], e[j]);
    }

    float s = 0.0f;
#pragma unroll
    for (int j = 0; j < EMB; ++j) s = fmaf(e[j], e[j], s);
    float nrm = sqrtf(s);
    float inv = 1.0f / fmaxf(nrm, 1e-12f);

    float* ho = Hout + (size_t)row * EMB;
    float* hn = Hn + (size_t)row * EMB;
#pragma unroll
    for (int j = 0; j < EMB; ++j) ho[j] = e[j];
#pragma unroll
    for (int j = 0; j < EMB; ++j) hn[j] = e[j] * inv;
}

// ---------------- fused logits + row softmax over N×N --------------------
__device__ __forceinline__ float dot16(const float4 a[4], float4 b0, float4 b1,
                                       float4 b2, float4 b3)
{
    float s;
    s = a[0].x * b0.x;
    s = fmaf(a[0].y, b0.y, s);
    s = fmaf(a[0].z, b0.z, s);
    s = fmaf(a[0].w, b0.w, s);
    s = fmaf(a[1].x, b1.x, s);
    s = fmaf(a[1].y, b1.y, s);
    s = fmaf(a[1].z, b1.z, s);
    s = fmaf(a[1].w, b1.w, s);
    s = fmaf(a[2].x, b2.x, s);
    s = fmaf(a[2].y, b2.y, s);
    s = fmaf(a[2].z, b2.z, s);
    s = fmaf(a[2].w, b2.w, s);
    s = fmaf(a[3].x, b3.x, s);
    s = fmaf(a[3].y, b3.y, s);
    s = fmaf(a[3].z, b3.z, s);
    s = fmaf(a[3].w, b3.w, s);
    return s;
}

__global__ __launch_bounds__(TB, 2) void softmax_kernel(
    const float* __restrict__ A, const float* __restrict__ Hn,
    const float* __restrict__ p_log_tau, const float* __restrict__ p_raw_alpha,
    float* __restrict__ Wout)
{
    const int t = threadIdx.x;
    const int row0 = blockIdx.x * RB;

    const float tau = fminf(fmaxf(__expf(p_log_tau[0]), 0.1f), 10.0f);
    const float alpha = 1.0f / (1.0f + __expf(-p_raw_alpha[0]));
    const float cl = (1.0f - alpha) / tau;

    // Hn rows of this block -> registers (row index clamped for tail block)
    float4 hi[RB][4];
#pragma unroll
    for (int r = 0; r < RB; ++r) {
        int row = row0 + r;
        if (row >= N_NODES) row = N_NODES - 1;
        const float4* hp = (const float4*)(Hn + (size_t)row * EMB);
#pragma unroll
        for (int p = 0; p < 4; ++p) hi[r][p] = hp[p];
    }

    const float4* Hn4 = (const float4*)Hn;

    float x[RB][CHUNKS * 4];
    float mloc[RB];
#pragma unroll
    for (int r = 0; r < RB; ++r) mloc[r] = -INFINITY;

#pragma unroll
    for (int c = 0; c < CHUNKS; ++c) {
        const int f4 = c * TB + t;
        const bool valid = f4 < NF4;
        const int f4c = valid ? f4 : 0;

        fx4 av[RB];
#pragma unroll
        for (int r = 0; r < RB; ++r) {
            int row = row0 + r;
            if (row >= N_NODES) row = N_NODES - 1;
            const fx4* ap = (const fx4*)(A + (size_t)row * N_NODES);
            av[r] = __builtin_nontemporal_load(&ap[f4c]);
        }

#pragma unroll
        for (int d = 0; d < 4; ++d) {
            const int j = f4c * 4 + d;
            float4 b0 = Hn4[j * 4 + 0];
            float4 b1 = Hn4[j * 4 + 1];
            float4 b2 = Hn4[j * 4 + 2];
            float4 b3 = Hn4[j * 4 + 3];
#pragma unroll
            for (int r = 0; r < RB; ++r) {
                float dotv = dot16(hi[r], b0, b1, b2, b3);
                float a = (d == 0) ? av[r].x
                        : (d == 1) ? av[r].y
                        : (d == 2) ? av[r].z
                                   : av[r].w;
                float xv = fmaf(cl, dotv, alpha * __logf(a + 1e-12f));
                xv = valid ? xv : -INFINITY;
                x[r][c * 4 + d] = xv;
                mloc[r] = fmaxf(mloc[r], xv);
            }
        }
    }

    // ---- block reduction: max per row ----
    __shared__ float red[RB][TB / 64];
    __shared__ float rowval[RB];
    const int lane = t & 63;
    const int wave = t >> 6;

#pragma unroll
    for (int r = 0; r < RB; ++r) {
        float v = mloc[r];
#pragma unroll
        for (int off = 32; off >= 1; off >>= 1) v = fmaxf(v, __shfl_down(v, off, 64));
        if (lane == 0) red[r][wave] = v;
    }
    __syncthreads();
    if (t < RB) {
        float v = red[t][0];
#pragma unroll
        for (int w = 1; w < TB / 64; ++w) v = fmaxf(v, red[t][w]);
        rowval[t] = v;
    }
    __syncthreads();
    float mrow[RB];
#pragma unroll
    for (int r = 0; r < RB; ++r) mrow[r] = rowval[r];

    // ---- exponentiate in registers, accumulate local sums ----
    float sloc[RB];
#pragma unroll
    for (int r = 0; r < RB; ++r) sloc[r] = 0.0f;
#pragma unroll
    for (int c = 0; c < CHUNKS; ++c) {
#pragma unroll
        for (int d = 0; d < 4; ++d) {
#pragma unroll
            for (int r = 0; r < RB; ++r) {
                float e = __expf(x[r][c * 4 + d] - mrow[r]);  // -inf -> 0
                x[r][c * 4 + d] = e;
                sloc[r] += e;
            }
        }
    }

    // ---- block reduction: sum per row ----
#pragma unroll
    for (int r = 0; r < RB; ++r) {
        float v = sloc[r];
#pragma unroll
        for (int off = 32; off >= 1; off >>= 1) v += __shfl_down(v, off, 64);
        if (lane == 0) red[r][wave] = v;
    }
    __syncthreads();
    if (t < RB) {
        float v = red[t][0];
#pragma unroll
        for (int w = 1; w < TB / 64; ++w) v += red[t][w];
        rowval[t] = v;
    }
    __syncthreads();
    float invl[RB];
#pragma unroll
    for (int r = 0; r < RB; ++r) invl[r] = 1.0f / rowval[r];

    // ---- normalized writes (coalesced float4, nontemporal) ----
#pragma unroll
    for (int c = 0; c < CHUNKS; ++c) {
        const int f4 = c * TB + t;
        if (f4 < NF4) {
#pragma unroll
            for (int r = 0; r < RB; ++r) {
                const int row = row0 + r;
                if (row < N_NODES) {
                    fx4 o;
                    o.x = x[r][c * 4 + 0] * invl[r];
                    o.y = x[r][c * 4 + 1] * invl[r];
                    o.z = x[r][c * 4 + 2] * invl[r];
                    o.w = x[r][c * 4 + 3] * invl[r];
                    fx4* wp = (fx4*)(Wout + (size_t)row * N_NODES);
                    __builtin_nontemporal_store(o, &wp[f4]);
                }
            }
        }
    }
}

extern "C" void kernel_launch(void* const* d_in, const int* in_sizes, int n_in,
                              void* d_out, int out_size, void* d_ws, size_t ws_size,
                              hipStream_t stream) {
    const float* X        = (const float*)d_in[0];
    const float* A        = (const float*)d_in[1];
    const float* W1       = (const float*)d_in[2];
    const float* b1       = (const float*)d_in[3];
    const float* W2       = (const float*)d_in[4];
    const float* b2       = (const float*)d_in[5];
    const float* log_tau  = (const float*)d_in[6];
    const float* raw_alpha= (const float*)d_in[7];

    float* Wout = (float*)d_out;
    float* Hout = (float*)d_out + (size_t)N_NODES * N_NODES;
    float* Hn   = (float*)d_ws;   // 10000*16 floats = 640 KB scratch

    encoder_kernel<<<(N_NODES + 255) / 256, 256, 0, stream>>>(X, W1, b1, W2, b2, Hout, Hn);

    const int nb = (N_NODES + RB - 1) / RB;
    softmax_kernel<<<nb, TB, 0, stream>>>(A, Hn, log_tau, raw_alpha, Wout);
}